// Round 7
// baseline (516.389 us; speedup 1.0000x reference)
//
#include <hip/hip_runtime.h>

#define N_PTS 200000
#define GRIDL 192
#define CAP 8192            // per-tap bin capacity (mean ~5651)
#define NREG 216            // 6^3 regions of 32^3 cells
#define RCAP 1152           // per-region point capacity (mean ~926, sigma ~30)
#define NSLICE 9            // enum: 9 slices of 128 points cover RCAP
#define SCAP 32             // per-(slice,tap) LDS stage (mean 5.6; P(>32) ~ 1e-16)

// ---- workspace layout (bytes), all 16-aligned; ~39.7 MB total ----
#define VOL_OFF   0ull
#define VOL_BYTES (192ull*192ull*192ull*4ull)   // 28,311,552
#define BINS_OFF  28311552ull                   // 125*8192*8 = 8,192,000
#define BCNT_OFF  36503552ull                   // 125*32*4 = 16,000 (128B-padded)
#define RCNT_OFF  36519552ull                   // 216*32*4 = 27,648 (128B-padded)
#define PLIST_OFF 36547200ull                   // 216*1152*8 = 1,990,656
#define WBUF_OFF  38537856ull                   // 125*2304*4 = 1,152,000
#define VTAB_OFF  39689856ull                   // 125*16 = 2,000
#define A0_OFF    39691856ull                   // 4,096
#define A1_OFF    39695952ull                   // 1,024

// 80 live taps (1 <= ||off||^2 <= 6)
struct TapTable { int p[80]; };
__host__ __device__ constexpr TapTable make_taps() {
    TapTable tt{}; int t = 0;
    for (int a = -2; a <= 2; a++)
        for (int b = -2; b <= 2; b++)
            for (int c = -2; c <= 2; c++) {
                int sq = a*a + b*b + c*c;
                if (sq >= 1 && sq <= 6) tt.p[t++] = (a+2)*25 + (b+2)*5 + (c+2);
            }
    return tt;
}
__device__ const TapTable TAPS = make_taps();

// ============================================================
// Kernel 1: build scaled structured weights + fused sc matrices
// ============================================================
__global__ void prep_kernel(const float* __restrict__ wt, const float* __restrict__ wsc0,
                            const float* __restrict__ wsc1, float* __restrict__ wbuf,
                            float* __restrict__ vtab, float* __restrict__ A0,
                            float* __restrict__ A1) {
    int p = blockIdx.x;
    int dx = p / 25 - 2, dy = (p / 5) % 5 - 2, dz = p % 5 - 2;
    double d = sqrt((double)(dx*dx + dy*dy + dz*dz));
    const double step = 2.5 / 9.0;
    const double cst = 1.14136 * exp(2.0);
    float emb[8];
#pragma unroll
    for (int r = 0; r < 8; r++) {
        double t = (d - (double)(r + 1) * step) / step;
        double tt = t * t;
        emb[r] = (tt < 1.0) ? (float)(cst * exp(-2.0 / (1.0 - tt))) : 0.0f;
    }
    if (threadIdx.x == 0) {
        float inv = (d > 0.0) ? (float)(sqrt(3.0) / d) : 0.0f;
        vtab[p*4+0] = dx * inv; vtab[p*4+1] = dy * inv;
        vtab[p*4+2] = dz * inv; vtab[p*4+3] = 0.0f;
    }
    const float ALPHA = 0.14433756729740643f;   // 1/sqrt(48)
    for (int q = threadIdx.x; q < 2304; q += blockDim.x) {
        float acc = 0.0f;
#pragma unroll
        for (int r = 0; r < 8; r++) acc = fmaf(emb[r], wt[r*2304 + q], acc);
        acc *= (1.0f / 125.0f);
        float val = acc * ((q < 1792) ? ALPHA : (1.0f / 12.0f));
        wbuf[p*2304 + q] = val;
        if (p == 62) {  // center tap: val==0 (EMB(0)=0); fold sc matrices
            if (q < 1024)                   A0[q]        = wsc0[q] * 0.17677669529663687f + val;
            else if (q >= 1536 && q < 1792) A1[q-1536]   = wsc1[q-1536] * 0.25f + val;
        }
    }
}

// ============================================================
// Kernel 2: scatter (two-pass LDS histogram, padded global atomics)
// ============================================================
__global__ __launch_bounds__(256) void scatter_kernel(const int* __restrict__ coords,
        int* __restrict__ vol, int* __restrict__ rcnt_pad, int2* __restrict__ plist) {
    __shared__ int hist[216];
    __shared__ int rbase[216];
    for (int i = threadIdx.x; i < 216; i += 256) hist[i] = 0;
    __syncthreads();
    for (int n = blockIdx.x * 256 + threadIdx.x; n < N_PTS; n += 65536) {
        int x = coords[n*3], y = coords[n*3+1], z = coords[n*3+2];
        vol[(x * GRIDL + y) * GRIDL + z] = n;
        int r = (x >> 5) * 36 + (y >> 5) * 6 + (z >> 5);
        atomicAdd(&hist[r], 1);
    }
    __syncthreads();
    if (threadIdx.x < 216) {
        int c = hist[threadIdx.x];
        rbase[threadIdx.x] = c ? atomicAdd(&rcnt_pad[threadIdx.x * 32], c) : 0;
        hist[threadIdx.x] = 0;   // reuse as cursor
    }
    __syncthreads();
    for (int n = blockIdx.x * 256 + threadIdx.x; n < N_PTS; n += 65536) {
        int x = coords[n*3], y = coords[n*3+1], z = coords[n*3+2];
        int r = (x >> 5) * 36 + (y >> 5) * 6 + (z >> 5);
        int j = rbase[r] + atomicAdd(&hist[r], 1);
        if (j < RCAP) plist[r * RCAP + j] = make_int2(n, (x << 16) | (y << 8) | z);
    }
}

// ============================================================
// Kernel 3: enumerate hits (unchanged from R6)
// ============================================================
__global__ __launch_bounds__(128) void enum_kernel(const int* __restrict__ vol,
        const int* __restrict__ rcnt_pad, const int2* __restrict__ plist,
        int* __restrict__ bcnt_pad, int2* __restrict__ bins) {
    int r = blockIdx.x / NSLICE, s = blockIdx.x % NSLICE;
    int cnt = min(rcnt_pad[r * 32], RCAP);
    int lo = s * 128, hi = min(cnt, lo + 128);
    if (lo >= hi) return;                      // block-uniform exit
    __shared__ int2 stage[80][SCAP];           // 20,480 B
    __shared__ int hist[80];
    __shared__ int tbase[80];
    if (threadIdx.x < 80) hist[threadIdx.x] = 0;
    __syncthreads();

    int idx = lo + threadIdx.x;
    bool act = idx < hi;
    int n = -1, x = 0, y = 0, z = 0;
    if (act) {
        int2 e = plist[r * RCAP + idx];
        n = e.x; x = e.y >> 16; y = (e.y >> 8) & 255; z = e.y & 255;
    }
    int t = 0;
#pragma unroll
    for (int a = -2; a <= 2; a++)
#pragma unroll
    for (int b = -2; b <= 2; b++)
#pragma unroll
    for (int c = -2; c <= 2; c++) {
        int sq = a*a + b*b + c*c;
        if (sq < 1 || sq > 6) continue;        // dead tap: K==0
        int cx = x + a, cy = y + b, cz = z + c;
        if (act && ((unsigned)cx < 192u) && ((unsigned)cy < 192u) && ((unsigned)cz < 192u)) {
            int nb = vol[(cx * GRIDL + cy) * GRIDL + cz];
            if (nb >= 0) {
                int j = atomicAdd(&hist[t], 1);
                if (j < SCAP) stage[t][j] = make_int2(n, nb);
            }
        }
        t++;
    }
    __syncthreads();
    if (threadIdx.x < 80) {
        int c = min(hist[threadIdx.x], SCAP);
        tbase[threadIdx.x] = c ? atomicAdd(&bcnt_pad[TAPS.p[threadIdx.x] * 32], c) : 0;
    }
    __syncthreads();
    // coalesced copy-out: 4 tap-groups in parallel, 20 taps each
    int g = threadIdx.x >> 5, l = threadIdx.x & 31;
    for (int q = 0; q < 20; q++) {
        int t2 = g * 20 + q;
        int c = min(hist[t2], SCAP);
        if (l < c) {
            int pos = tbase[t2] + l;
            if (pos < CAP) bins[TAPS.p[t2] * CAP + pos] = stage[t2][l];
        }
    }
}

// ============================================================
// Kernel 4: out[n] = sc(feats[n])  (fully initializes d_out)
// ============================================================
__global__ __launch_bounds__(256) void sc_self_kernel(const float* __restrict__ feats,
        const float* __restrict__ A0, const float* __restrict__ A1,
        float* __restrict__ out) {
    __shared__ __align__(16) float sA0[1024];
    __shared__ __align__(16) float sA1[256];
    for (int i = threadIdx.x; i < 1024; i += 256) sA0[i] = A0[i];
    if (threadIdx.x < 256) sA1[threadIdx.x] = A1[threadIdx.x];
    __syncthreads();
    int n = blockIdx.x * 256 + threadIdx.x;
    if (n >= N_PTS) return;
    const float4* fr = (const float4*)(feats + (size_t)n * 80);
    float4* orow = (float4*)(out + (size_t)n * 80);
    float f0[32];
#pragma unroll
    for (int j = 0; j < 8; j++) {
        float4 t = fr[j];
        f0[4*j] = t.x; f0[4*j+1] = t.y; f0[4*j+2] = t.z; f0[4*j+3] = t.w;
    }
    float a0[32];
#pragma unroll
    for (int k = 0; k < 32; k++) a0[k] = 0.0f;
#pragma unroll
    for (int i = 0; i < 32; i++) {
        float fv = f0[i];
#pragma unroll
        for (int k4 = 0; k4 < 8; k4++) {
            float4 w = ((const float4*)sA0)[i*8 + k4];
            a0[4*k4]   = fmaf(fv, w.x, a0[4*k4]);
            a0[4*k4+1] = fmaf(fv, w.y, a0[4*k4+1]);
            a0[4*k4+2] = fmaf(fv, w.z, a0[4*k4+2]);
            a0[4*k4+3] = fmaf(fv, w.w, a0[4*k4+3]);
        }
    }
#pragma unroll
    for (int j = 0; j < 8; j++) orow[j] = make_float4(a0[4*j], a0[4*j+1], a0[4*j+2], a0[4*j+3]);
    float f1[48];
#pragma unroll
    for (int j = 0; j < 12; j++) {
        float4 t = fr[8 + j];
        f1[4*j] = t.x; f1[4*j+1] = t.y; f1[4*j+2] = t.z; f1[4*j+3] = t.w;
    }
    float a1[48];
#pragma unroll
    for (int k = 0; k < 48; k++) a1[k] = 0.0f;
#pragma unroll
    for (int i = 0; i < 16; i++) {
        float fm0 = f1[3*i], fm1 = f1[3*i+1], fm2 = f1[3*i+2];
#pragma unroll
        for (int k4 = 0; k4 < 4; k4++) {
            float4 w = ((const float4*)sA1)[i*4 + k4];
            const float* wp = (const float*)&w;
#pragma unroll
            for (int kk = 0; kk < 4; kk++) {
                int k = 4*k4 + kk;
                a1[3*k]   = fmaf(fm0, wp[kk], a1[3*k]);
                a1[3*k+1] = fmaf(fm1, wp[kk], a1[3*k+1]);
                a1[3*k+2] = fmaf(fm2, wp[kk], a1[3*k+2]);
            }
        }
    }
#pragma unroll
    for (int j = 0; j < 12; j++) orow[8+j] = make_float4(a1[4*j], a1[4*j+1], a1[4*j+2], a1[4*j+3]);
}

// ============================================================
// Kernel 5: per-tap structured apply. BARRIER-FREE hot loop:
// 4 independent waves per block; each wave stages into its PRIVATE
// ys[wv] slice (within-wave LDS ops are in-order -> no __syncthreads),
// destinations broadcast via __shfl, atomics fire-and-forget (only the
// end-of-kernel vmcnt drain remains).
// ============================================================
__global__ __launch_bounds__(256) void bin_kernel(const float* __restrict__ feats,
        const float* __restrict__ wbuf, const float* __restrict__ vtab,
        const int* __restrict__ bcnt_pad, const int2* __restrict__ bins,
        float* __restrict__ out) {
    int p = blockIdx.x >> 3;            // 125 taps x 8 chunks of 1024 hits
    int chunk = blockIdx.x & 7;
    int cnt = min(bcnt_pad[p * 32], CAP);
    int start = chunk * 1024;
    if (start >= cnt) return;

    __shared__ __align__(16) float sW[2304];
    __shared__ float sv[4];
    __shared__ __align__(16) float ys[4][16][81];   // per-wave private, 20,736 B

    for (int i = threadIdx.x; i < 2304; i += 256) sW[i] = wbuf[p*2304 + i];
    if (threadIdx.x < 4) sv[threadIdx.x] = vtab[p*4 + threadIdx.x];
    __syncthreads();                    // the only block-wide barrier

    int wv = threadIdx.x >> 6, lane = threadIdx.x & 63;
    const float4* sW1 = (const float4*)sW;            // [32][8]
    const float4* sW2 = (const float4*)(sW + 1024);   // [32][4]
    const float4* sW3 = (const float4*)(sW + 1536);   // [16][4]
    const float4* sW4 = (const float4*)(sW + 1792);   // [16][8]
    float v0 = sv[0], v1 = sv[1], v2 = sv[2];

    for (int it = 0; it < 4; it++) {
        int h = start + wv * 256 + it * 64 + lane;
        bool act = h < cnt;
        int n = -1, nb = 0;
        if (act) { int2 e = bins[p*CAP + h]; n = e.x; nb = e.y; }

        const float4* fr = (const float4*)(feats + (size_t)nb * 80);
        float f0[32], f1[48];
#pragma unroll
        for (int j = 0; j < 8; j++) {
            float4 t = fr[j];
            f0[4*j] = t.x; f0[4*j+1] = t.y; f0[4*j+2] = t.z; f0[4*j+3] = t.w;
        }
#pragma unroll
        for (int j = 0; j < 12; j++) {
            float4 t = fr[8 + j];
            f1[4*j] = t.x; f1[4*j+1] = t.y; f1[4*j+2] = t.z; f1[4*j+3] = t.w;
        }
        float g[16];
#pragma unroll
        for (int i = 0; i < 16; i++)
            g[i] = f1[3*i]*v0 + f1[3*i+1]*v1 + f1[3*i+2]*v2;

        float a0[32], cc[16];
#pragma unroll
        for (int k = 0; k < 32; k++) a0[k] = 0.0f;
#pragma unroll
        for (int k = 0; k < 16; k++) cc[k] = 0.0f;
#pragma unroll
        for (int i = 0; i < 32; i++) {
            float fv = f0[i];
#pragma unroll
            for (int k4 = 0; k4 < 8; k4++) {
                float4 w = sW1[i*8 + k4];
                a0[4*k4]   = fmaf(fv, w.x, a0[4*k4]);
                a0[4*k4+1] = fmaf(fv, w.y, a0[4*k4+1]);
                a0[4*k4+2] = fmaf(fv, w.z, a0[4*k4+2]);
                a0[4*k4+3] = fmaf(fv, w.w, a0[4*k4+3]);
            }
#pragma unroll
            for (int k4 = 0; k4 < 4; k4++) {
                float4 w = sW2[i*4 + k4];
                cc[4*k4]   = fmaf(fv, w.x, cc[4*k4]);
                cc[4*k4+1] = fmaf(fv, w.y, cc[4*k4+1]);
                cc[4*k4+2] = fmaf(fv, w.z, cc[4*k4+2]);
                cc[4*k4+3] = fmaf(fv, w.w, cc[4*k4+3]);
            }
        }
#pragma unroll
        for (int i = 0; i < 16; i++) {
            float gv = g[i];
#pragma unroll
            for (int k4 = 0; k4 < 8; k4++) {
                float4 w = sW4[i*8 + k4];
                a0[4*k4]   = fmaf(gv, w.x, a0[4*k4]);
                a0[4*k4+1] = fmaf(gv, w.y, a0[4*k4+1]);
                a0[4*k4+2] = fmaf(gv, w.z, a0[4*k4+2]);
                a0[4*k4+3] = fmaf(gv, w.w, a0[4*k4+3]);
            }
        }
        float a1[48];
#pragma unroll
        for (int k = 0; k < 16; k++) {
            a1[3*k] = v0 * cc[k]; a1[3*k+1] = v1 * cc[k]; a1[3*k+2] = v2 * cc[k];
        }
#pragma unroll
        for (int i = 0; i < 16; i++) {
            float fm0 = f1[3*i], fm1 = f1[3*i+1], fm2 = f1[3*i+2];
#pragma unroll
            for (int k4 = 0; k4 < 4; k4++) {
                float4 w = sW3[i*4 + k4];
                const float* wp = (const float*)&w;
#pragma unroll
                for (int kk = 0; kk < 4; kk++) {
                    int k = 4*k4 + kk;
                    a1[3*k]   = fmaf(fm0, wp[kk], a1[3*k]);
                    a1[3*k+1] = fmaf(fm1, wp[kk], a1[3*k+1]);
                    a1[3*k+2] = fmaf(fm2, wp[kk], a1[3*k+2]);
                }
            }
        }

        // 4-phase transpose flush through the wave-private LDS slice.
        // Within-wave DS ordering guarantees write->read; no barriers.
#pragma unroll
        for (int ph = 0; ph < 4; ph++) {
            if ((lane >> 4) == ph) {
                int rr = lane & 15;
                float* yr = &ys[wv][rr][0];
#pragma unroll
                for (int k = 0; k < 32; k++) yr[k] = a0[k];
#pragma unroll
                for (int k = 0; k < 48; k++) yr[32 + k] = a1[k];
            }
            for (int h2 = 0; h2 < 16; h2++) {
                int nn = __shfl(n, ph * 16 + h2, 64);   // wave-uniform
                if (nn < 0) continue;
                float* orow = out + (size_t)nn * 80;
                unsafeAtomicAdd(orow + lane, ys[wv][h2][lane]);
                if (lane < 16) unsafeAtomicAdd(orow + 64 + lane, ys[wv][h2][64 + lane]);
            }
        }
    }
}

extern "C" void kernel_launch(void* const* d_in, const int* in_sizes, int n_in,
                              void* d_out, int out_size, void* d_ws, size_t ws_size,
                              hipStream_t stream) {
    const float* feats = (const float*)d_in[0];
    const float* wt    = (const float*)d_in[1];
    const float* wsc0  = (const float*)d_in[2];
    const float* wsc1  = (const float*)d_in[3];
    const int*   coords= (const int*)d_in[4];
    float* out = (float*)d_out;
    char* ws = (char*)d_ws;

    int*   vol      = (int*)(ws + VOL_OFF);
    int2*  bins     = (int2*)(ws + BINS_OFF);
    int*   bcnt_pad = (int*)(ws + BCNT_OFF);
    int*   rcnt_pad = (int*)(ws + RCNT_OFF);
    int2*  plist    = (int2*)(ws + PLIST_OFF);
    float* wbuf     = (float*)(ws + WBUF_OFF);
    float* vtab     = (float*)(ws + VTAB_OFF);
    float* A0       = (float*)(ws + A0_OFF);
    float* A1       = (float*)(ws + A1_OFF);

    hipMemsetAsync(vol, 0xFF, VOL_BYTES, stream);            // -1 everywhere
    hipMemsetAsync(bcnt_pad, 0, 16000 + 27648, stream);      // bcnt + rcnt

    prep_kernel<<<125, 256, 0, stream>>>(wt, wsc0, wsc1, wbuf, vtab, A0, A1);
    scatter_kernel<<<256, 256, 0, stream>>>(coords, vol, rcnt_pad, plist);
    enum_kernel<<<NREG * NSLICE, 128, 0, stream>>>(vol, rcnt_pad, plist, bcnt_pad, bins);
    sc_self_kernel<<<(N_PTS + 255) / 256, 256, 0, stream>>>(feats, A0, A1, out);
    bin_kernel<<<125 * 8, 256, 0, stream>>>(feats, wbuf, vtab, bcnt_pad, bins, out);
}

// Round 8
// 487.514 us; speedup vs baseline: 1.0592x; 1.0592x over previous
//
#include <hip/hip_runtime.h>

#define N_PTS 200000
#define GRIDL 192
#define CAP 8192            // per-tap bin capacity (mean ~5651)
#define NREG 216            // 6^3 regions of 32^3 cells
#define RCAP 1152           // per-region point capacity (mean ~926, sigma ~30)
#define NSLICE 9            // enum: 9 slices of 128 points cover RCAP
#define SCAP 32             // per-(slice,tap) LDS stage (mean 5.6; P(>32) ~ 1e-16)

// ---- workspace layout (bytes); vol has 256B guard pads for z-row loads ----
#define VOL_OFF   256ull
#define VOL_BYTES (192ull*192ull*192ull*4ull)   // 28,311,552
#define BINS_OFF  28312064ull                   // 125*8192*8 = 8,192,000
#define BCNT_OFF  36504064ull                   // 125*32*4 = 16,000 (128B-padded)
#define RCNT_OFF  36520064ull                   // 216*32*4 = 27,648 (contiguous after bcnt)
#define PLIST_OFF 36547712ull                   // 216*1152*8 = 1,990,656
#define WBUF_OFF  38538368ull                   // 125*2304*4 = 1,152,000
#define VTAB_OFF  39690368ull                   // 125*16 = 2,000
#define A0_OFF    39692368ull                   // 4,096
#define A1_OFF    39696464ull                   // 1,024

// 80 live taps (1 <= ||off||^2 <= 6)
struct TapTable { int p[80]; };
__host__ __device__ constexpr TapTable make_taps() {
    TapTable tt{}; int t = 0;
    for (int a = -2; a <= 2; a++)
        for (int b = -2; b <= 2; b++)
            for (int c = -2; c <= 2; c++) {
                int sq = a*a + b*b + c*c;
                if (sq >= 1 && sq <= 6) tt.p[t++] = (a+2)*25 + (b+2)*5 + (c+2);
            }
    return tt;
}
__device__ const TapTable TAPS = make_taps();

// ============================================================
// Kernel 1: build scaled structured weights + fused sc matrices
// ============================================================
__global__ void prep_kernel(const float* __restrict__ wt, const float* __restrict__ wsc0,
                            const float* __restrict__ wsc1, float* __restrict__ wbuf,
                            float* __restrict__ vtab, float* __restrict__ A0,
                            float* __restrict__ A1) {
    int p = blockIdx.x;
    int dx = p / 25 - 2, dy = (p / 5) % 5 - 2, dz = p % 5 - 2;
    double d = sqrt((double)(dx*dx + dy*dy + dz*dz));
    const double step = 2.5 / 9.0;
    const double cst = 1.14136 * exp(2.0);
    float emb[8];
#pragma unroll
    for (int r = 0; r < 8; r++) {
        double t = (d - (double)(r + 1) * step) / step;
        double tt = t * t;
        emb[r] = (tt < 1.0) ? (float)(cst * exp(-2.0 / (1.0 - tt))) : 0.0f;
    }
    if (threadIdx.x == 0) {
        float inv = (d > 0.0) ? (float)(sqrt(3.0) / d) : 0.0f;
        vtab[p*4+0] = dx * inv; vtab[p*4+1] = dy * inv;
        vtab[p*4+2] = dz * inv; vtab[p*4+3] = 0.0f;
    }
    const float ALPHA = 0.14433756729740643f;   // 1/sqrt(48)
    for (int q = threadIdx.x; q < 2304; q += blockDim.x) {
        float acc = 0.0f;
#pragma unroll
        for (int r = 0; r < 8; r++) acc = fmaf(emb[r], wt[r*2304 + q], acc);
        acc *= (1.0f / 125.0f);
        float val = acc * ((q < 1792) ? ALPHA : (1.0f / 12.0f));
        wbuf[p*2304 + q] = val;
        if (p == 62) {  // center tap: val==0 (EMB(0)=0); fold sc matrices
            if (q < 1024)                   A0[q]        = wsc0[q] * 0.17677669529663687f + val;
            else if (q >= 1536 && q < 1792) A1[q-1536]   = wsc1[q-1536] * 0.25f + val;
        }
    }
}

// ============================================================
// Kernel 2: scatter (two-pass LDS histogram, padded global atomics)
// ============================================================
__global__ __launch_bounds__(256) void scatter_kernel(const int* __restrict__ coords,
        int* __restrict__ vol, int* __restrict__ rcnt_pad, int2* __restrict__ plist) {
    __shared__ int hist[216];
    __shared__ int rbase[216];
    for (int i = threadIdx.x; i < 216; i += 256) hist[i] = 0;
    __syncthreads();
    for (int n = blockIdx.x * 256 + threadIdx.x; n < N_PTS; n += 65536) {
        int x = coords[n*3], y = coords[n*3+1], z = coords[n*3+2];
        vol[(x * GRIDL + y) * GRIDL + z] = n;
        int r = (x >> 5) * 36 + (y >> 5) * 6 + (z >> 5);
        atomicAdd(&hist[r], 1);
    }
    __syncthreads();
    if (threadIdx.x < 216) {
        int c = hist[threadIdx.x];
        rbase[threadIdx.x] = c ? atomicAdd(&rcnt_pad[threadIdx.x * 32], c) : 0;
        hist[threadIdx.x] = 0;   // reuse as cursor
    }
    __syncthreads();
    for (int n = blockIdx.x * 256 + threadIdx.x; n < N_PTS; n += 65536) {
        int x = coords[n*3], y = coords[n*3+1], z = coords[n*3+2];
        int r = (x >> 5) * 36 + (y >> 5) * 6 + (z >> 5);
        int j = rbase[r] + atomicAdd(&hist[r], 1);
        if (j < RCAP) plist[r * RCAP + j] = make_int2(n, (x << 16) | (y << 8) | z);
    }
}

// ============================================================
// Kernel 3: enumerate hits. z-row probe: per (a,b) load vol[z-2..z+2]
// with one dwordx4 + one dword (4B-aligned; 256B guard pads make the
// +-8B overreach safe; junk values are masked by the per-element bounds
// check or are negative poison -> skipped). ~3x fewer L1/L2 line
// requests than 80 scalar probes.
// ============================================================
__global__ __launch_bounds__(128) void enum_kernel(const int* __restrict__ vol,
        const int* __restrict__ rcnt_pad, const int2* __restrict__ plist,
        int* __restrict__ bcnt_pad, int2* __restrict__ bins) {
    int r = blockIdx.x / NSLICE, s = blockIdx.x % NSLICE;
    int cnt = min(rcnt_pad[r * 32], RCAP);
    int lo = s * 128, hi = min(cnt, lo + 128);
    if (lo >= hi) return;                      // block-uniform exit
    __shared__ int2 stage[80][SCAP];           // 20,480 B
    __shared__ int hist[80];
    __shared__ int tbase[80];
    if (threadIdx.x < 80) hist[threadIdx.x] = 0;
    __syncthreads();

    int idx = lo + threadIdx.x;
    bool act = idx < hi;
    int n = -1, x = 0, y = 0, z = 0;
    if (act) {
        int2 e = plist[r * RCAP + idx];
        n = e.x; x = e.y >> 16; y = (e.y >> 8) & 255; z = e.y & 255;
    }
    int t = 0;
#pragma unroll
    for (int a = -2; a <= 2; a++) {
        int cx = x + a;
#pragma unroll
        for (int b = -2; b <= 2; b++) {
            int cy = y + b;
            bool okrow = act && ((unsigned)cx < 192u) && ((unsigned)cy < 192u);
            int4 v4 = make_int4(-1, -1, -1, -1);
            int v5 = -1;
            if (okrow) {
                const int* rowp = vol + ((cx * GRIDL + cy) * GRIDL + z);
                v4 = *reinterpret_cast<const int4*>(rowp - 2);   // z-2..z+1
                v5 = rowp[2];                                    // z+2
            }
#pragma unroll
            for (int c = -2; c <= 2; c++) {
                int sq = a*a + b*b + c*c;
                if (sq < 1 || sq > 6) continue;    // dead tap: K==0
                int nb = (c == -2) ? v4.x : (c == -1) ? v4.y :
                         (c ==  0) ? v4.z : (c ==  1) ? v4.w : v5;
                if (okrow && ((unsigned)(z + c) < 192u) && nb >= 0) {
                    int j = atomicAdd(&hist[t], 1);
                    if (j < SCAP) stage[t][j] = make_int2(n, nb);
                }
                t++;
            }
        }
    }
    __syncthreads();
    if (threadIdx.x < 80) {
        int c = min(hist[threadIdx.x], SCAP);
        tbase[threadIdx.x] = c ? atomicAdd(&bcnt_pad[TAPS.p[threadIdx.x] * 32], c) : 0;
    }
    __syncthreads();
    // coalesced copy-out: 4 tap-groups in parallel, 20 taps each
    int g = threadIdx.x >> 5, l = threadIdx.x & 31;
    for (int q = 0; q < 20; q++) {
        int t2 = g * 20 + q;
        int c = min(hist[t2], SCAP);
        if (l < c) {
            int pos = tbase[t2] + l;
            if (pos < CAP) bins[TAPS.p[t2] * CAP + pos] = stage[t2][l];
        }
    }
}

// ============================================================
// Kernel 4: out[n] = sc(feats[n])  (fully initializes d_out)
// ============================================================
__global__ __launch_bounds__(256) void sc_self_kernel(const float* __restrict__ feats,
        const float* __restrict__ A0, const float* __restrict__ A1,
        float* __restrict__ out) {
    __shared__ __align__(16) float sA0[1024];
    __shared__ __align__(16) float sA1[256];
    for (int i = threadIdx.x; i < 1024; i += 256) sA0[i] = A0[i];
    if (threadIdx.x < 256) sA1[threadIdx.x] = A1[threadIdx.x];
    __syncthreads();
    int n = blockIdx.x * 256 + threadIdx.x;
    if (n >= N_PTS) return;
    const float4* fr = (const float4*)(feats + (size_t)n * 80);
    float4* orow = (float4*)(out + (size_t)n * 80);
    float f0[32];
#pragma unroll
    for (int j = 0; j < 8; j++) {
        float4 t = fr[j];
        f0[4*j] = t.x; f0[4*j+1] = t.y; f0[4*j+2] = t.z; f0[4*j+3] = t.w;
    }
    float a0[32];
#pragma unroll
    for (int k = 0; k < 32; k++) a0[k] = 0.0f;
#pragma unroll
    for (int i = 0; i < 32; i++) {
        float fv = f0[i];
#pragma unroll
        for (int k4 = 0; k4 < 8; k4++) {
            float4 w = ((const float4*)sA0)[i*8 + k4];
            a0[4*k4]   = fmaf(fv, w.x, a0[4*k4]);
            a0[4*k4+1] = fmaf(fv, w.y, a0[4*k4+1]);
            a0[4*k4+2] = fmaf(fv, w.z, a0[4*k4+2]);
            a0[4*k4+3] = fmaf(fv, w.w, a0[4*k4+3]);
        }
    }
#pragma unroll
    for (int j = 0; j < 8; j++) orow[j] = make_float4(a0[4*j], a0[4*j+1], a0[4*j+2], a0[4*j+3]);
    float f1[48];
#pragma unroll
    for (int j = 0; j < 12; j++) {
        float4 t = fr[8 + j];
        f1[4*j] = t.x; f1[4*j+1] = t.y; f1[4*j+2] = t.z; f1[4*j+3] = t.w;
    }
    float a1[48];
#pragma unroll
    for (int k = 0; k < 48; k++) a1[k] = 0.0f;
#pragma unroll
    for (int i = 0; i < 16; i++) {
        float fm0 = f1[3*i], fm1 = f1[3*i+1], fm2 = f1[3*i+2];
#pragma unroll
        for (int k4 = 0; k4 < 4; k4++) {
            float4 w = ((const float4*)sA1)[i*4 + k4];
            const float* wp = (const float*)&w;
#pragma unroll
            for (int kk = 0; kk < 4; kk++) {
                int k = 4*k4 + kk;
                a1[3*k]   = fmaf(fm0, wp[kk], a1[3*k]);
                a1[3*k+1] = fmaf(fm1, wp[kk], a1[3*k+1]);
                a1[3*k+2] = fmaf(fm2, wp[kk], a1[3*k+2]);
            }
        }
    }
#pragma unroll
    for (int j = 0; j < 12; j++) orow[8+j] = make_float4(a1[4*j], a1[4*j+1], a1[4*j+2], a1[4*j+3]);
}

// ============================================================
// Kernel 5: per-tap structured apply, SOFTWARE-PIPELINED.
// 1-wave blocks; bin entries prefetched 2 iterations ahead, feats rows
// 1 iteration ahead -> the ~5800-cycle compute phase hides the scattered
// gather latency. Barrier-free wave-private LDS transpose flush (R7).
// ============================================================
__global__ __launch_bounds__(64, 2) void bin_kernel(const float* __restrict__ feats,
        const float* __restrict__ wbuf, const float* __restrict__ vtab,
        const int* __restrict__ bcnt_pad, const int2* __restrict__ bins,
        float* __restrict__ out) {
    int p = blockIdx.x >> 4;            // 125 taps x 16 chunks of 512 hits
    int chunk = blockIdx.x & 15;
    int cnt = min(bcnt_pad[p * 32], CAP);
    int start = chunk * 512;
    if (start >= cnt) return;

    __shared__ __align__(16) float sW[2304];
    __shared__ __align__(16) float ys[16][81];   // wave-private transpose buffer

    int lane = threadIdx.x;
    {   // stage weights: 576 float4s, 9 per lane (single wave: no barrier needed)
        const float4* src = (const float4*)(wbuf + p*2304);
        float4* dstp = (float4*)sW;
#pragma unroll
        for (int j = 0; j < 9; j++) dstp[j*64 + lane] = src[j*64 + lane];
    }
    float v0 = vtab[p*4+0], v1 = vtab[p*4+1], v2 = vtab[p*4+2];  // uniform -> s_load

    const float4* sW1 = (const float4*)sW;            // [32][8]
    const float4* sW2 = (const float4*)(sW + 1024);   // [32][4]
    const float4* sW3 = (const float4*)(sW + 1536);   // [16][4]
    const float4* sW4 = (const float4*)(sW + 1792);   // [16][8]

    int nIter = (min(cnt - start, 512) + 63) >> 6;

    // ---- pipeline prologue ----
    int h0 = start + lane;
    int2 e_cur = (h0 < cnt) ? bins[p*CAP + h0] : make_int2(-1, 0);
    float4 fc[20];
    {
        const float4* fr = (const float4*)(feats + (size_t)e_cur.y * 80);
#pragma unroll
        for (int j = 0; j < 20; j++) fc[j] = fr[j];
    }
    int h1 = h0 + 64;
    int2 e_nxt = (h1 < cnt) ? bins[p*CAP + h1] : make_int2(-1, 0);

    for (int it = 0; it < nIter; it++) {
        // ---- issue prefetches: feats for it+1, bin entry for it+2 ----
        float4 fn[20];
        {
            const float4* fr = (const float4*)(feats + (size_t)e_nxt.y * 80);
#pragma unroll
            for (int j = 0; j < 20; j++) fn[j] = fr[j];
        }
        int h2 = start + (it + 2) * 64 + lane;
        int2 e_n2 = (h2 < cnt) ? bins[p*CAP + h2] : make_int2(-1, 0);

        int n = e_cur.x;

        // ---- unpack current feats ----
        float f0[32], f1[48];
#pragma unroll
        for (int j = 0; j < 8; j++) {
            f0[4*j] = fc[j].x; f0[4*j+1] = fc[j].y; f0[4*j+2] = fc[j].z; f0[4*j+3] = fc[j].w;
        }
#pragma unroll
        for (int j = 0; j < 12; j++) {
            f1[4*j] = fc[8+j].x; f1[4*j+1] = fc[8+j].y; f1[4*j+2] = fc[8+j].z; f1[4*j+3] = fc[8+j].w;
        }
        float g[16];
#pragma unroll
        for (int i = 0; i < 16; i++)
            g[i] = f1[3*i]*v0 + f1[3*i+1]*v1 + f1[3*i+2]*v2;

        float a0[32], cc[16];
#pragma unroll
        for (int k = 0; k < 32; k++) a0[k] = 0.0f;
#pragma unroll
        for (int k = 0; k < 16; k++) cc[k] = 0.0f;
#pragma unroll
        for (int i = 0; i < 32; i++) {
            float fv = f0[i];
#pragma unroll
            for (int k4 = 0; k4 < 8; k4++) {
                float4 w = sW1[i*8 + k4];
                a0[4*k4]   = fmaf(fv, w.x, a0[4*k4]);
                a0[4*k4+1] = fmaf(fv, w.y, a0[4*k4+1]);
                a0[4*k4+2] = fmaf(fv, w.z, a0[4*k4+2]);
                a0[4*k4+3] = fmaf(fv, w.w, a0[4*k4+3]);
            }
#pragma unroll
            for (int k4 = 0; k4 < 4; k4++) {
                float4 w = sW2[i*4 + k4];
                cc[4*k4]   = fmaf(fv, w.x, cc[4*k4]);
                cc[4*k4+1] = fmaf(fv, w.y, cc[4*k4+1]);
                cc[4*k4+2] = fmaf(fv, w.z, cc[4*k4+2]);
                cc[4*k4+3] = fmaf(fv, w.w, cc[4*k4+3]);
            }
        }
#pragma unroll
        for (int i = 0; i < 16; i++) {
            float gv = g[i];
#pragma unroll
            for (int k4 = 0; k4 < 8; k4++) {
                float4 w = sW4[i*8 + k4];
                a0[4*k4]   = fmaf(gv, w.x, a0[4*k4]);
                a0[4*k4+1] = fmaf(gv, w.y, a0[4*k4+1]);
                a0[4*k4+2] = fmaf(gv, w.z, a0[4*k4+2]);
                a0[4*k4+3] = fmaf(gv, w.w, a0[4*k4+3]);
            }
        }
        float a1[48];
#pragma unroll
        for (int k = 0; k < 16; k++) {
            a1[3*k] = v0 * cc[k]; a1[3*k+1] = v1 * cc[k]; a1[3*k+2] = v2 * cc[k];
        }
#pragma unroll
        for (int i = 0; i < 16; i++) {
            float fm0 = f1[3*i], fm1 = f1[3*i+1], fm2 = f1[3*i+2];
#pragma unroll
            for (int k4 = 0; k4 < 4; k4++) {
                float4 w = sW3[i*4 + k4];
                const float* wp = (const float*)&w;
#pragma unroll
                for (int kk = 0; kk < 4; kk++) {
                    int k = 4*k4 + kk;
                    a1[3*k]   = fmaf(fm0, wp[kk], a1[3*k]);
                    a1[3*k+1] = fmaf(fm1, wp[kk], a1[3*k+1]);
                    a1[3*k+2] = fmaf(fm2, wp[kk], a1[3*k+2]);
                }
            }
        }

        // ---- 4-phase barrier-free transpose flush (wave-private ys) ----
#pragma unroll
        for (int ph = 0; ph < 4; ph++) {
            if ((lane >> 4) == ph) {
                int rr = lane & 15;
                float* yr = &ys[rr][0];
#pragma unroll
                for (int k = 0; k < 32; k++) yr[k] = a0[k];
#pragma unroll
                for (int k = 0; k < 48; k++) yr[32 + k] = a1[k];
            }
            for (int h3 = 0; h3 < 16; h3++) {
                int nn = __shfl(n, ph * 16 + h3, 64);   // wave-uniform
                if (nn < 0) continue;
                float* orow = out + (size_t)nn * 80;
                unsafeAtomicAdd(orow + lane, ys[h3][lane]);
                if (lane < 16) unsafeAtomicAdd(orow + 64 + lane, ys[h3][64 + lane]);
            }
        }

        // ---- rotate pipeline ----
        e_cur = e_nxt; e_nxt = e_n2;
#pragma unroll
        for (int j = 0; j < 20; j++) fc[j] = fn[j];
    }
}

extern "C" void kernel_launch(void* const* d_in, const int* in_sizes, int n_in,
                              void* d_out, int out_size, void* d_ws, size_t ws_size,
                              hipStream_t stream) {
    const float* feats = (const float*)d_in[0];
    const float* wt    = (const float*)d_in[1];
    const float* wsc0  = (const float*)d_in[2];
    const float* wsc1  = (const float*)d_in[3];
    const int*   coords= (const int*)d_in[4];
    float* out = (float*)d_out;
    char* ws = (char*)d_ws;

    int*   vol      = (int*)(ws + VOL_OFF);
    int2*  bins     = (int2*)(ws + BINS_OFF);
    int*   bcnt_pad = (int*)(ws + BCNT_OFF);
    int*   rcnt_pad = (int*)(ws + RCNT_OFF);
    int2*  plist    = (int2*)(ws + PLIST_OFF);
    float* wbuf     = (float*)(ws + WBUF_OFF);
    float* vtab     = (float*)(ws + VTAB_OFF);
    float* A0       = (float*)(ws + A0_OFF);
    float* A1       = (float*)(ws + A1_OFF);

    hipMemsetAsync(vol, 0xFF, VOL_BYTES, stream);            // -1 everywhere
    hipMemsetAsync(bcnt_pad, 0, 16000 + 27648, stream);      // bcnt + rcnt (contiguous)

    prep_kernel<<<125, 256, 0, stream>>>(wt, wsc0, wsc1, wbuf, vtab, A0, A1);
    scatter_kernel<<<256, 256, 0, stream>>>(coords, vol, rcnt_pad, plist);
    enum_kernel<<<NREG * NSLICE, 128, 0, stream>>>(vol, rcnt_pad, plist, bcnt_pad, bins);
    sc_self_kernel<<<(N_PTS + 255) / 256, 256, 0, stream>>>(feats, A0, A1, out);
    bin_kernel<<<125 * 16, 64, 0, stream>>>(feats, wbuf, vtab, bcnt_pad, bins, out);
}